// Round 1
// baseline (73.271 us; speedup 1.0000x reference)
//
#include <hip/hip_runtime.h>

#define BLK 256
#define NW 4   // waves per block = batches per block-iteration

__device__ __forceinline__ float relu_(float v) { return fmaxf(v, 0.f); }

// PAIRS_A = {0,0,4,1,2,2,6,3} ; PAIRS_B = {4,1,5,5,6,3,7,7} packed as nibbles
#define PA_PACK 0x36221400u
#define PB_PACK 0x77365514u

__global__ __launch_bounds__(BLK, 4) void frap_kernel(
    const float* __restrict__ x,
    const float* __restrict__ mask,
    const float* __restrict__ wv1, const float* __restrict__ bv1,
    const float* __restrict__ wv2, const float* __restrict__ bv2,
    const float* __restrict__ wp1, const float* __restrict__ bp1,
    const float* __restrict__ wp2, const float* __restrict__ bp2,
    const float* __restrict__ we,  const float* __restrict__ be,
    const float* __restrict__ wc1, const float* __restrict__ bc1,
    const float* __restrict__ wc2, const float* __restrict__ bc2,
    const float* __restrict__ wm1, const float* __restrict__ bm1,
    const float* __restrict__ wm2, const float* __restrict__ bm2,
    const float* __restrict__ wm3, const float* __restrict__ bm3,
    const float* __restrict__ wk1, const float* __restrict__ bk1,
    const float* __restrict__ wk2, const float* __restrict__ bk2,
    float* __restrict__ out, int Btot)
{
    __shared__ float s_sw[32];        // [veh:16 | pha:16] = w1(2),b1(2),w2(8),b2(4)
    __shared__ float s_we[128];       // [f][k] 8x16
    __shared__ float s_wc1[640];      // [32][20]
    __shared__ float s_bc1[20];
    __shared__ float s_be[16];
    __shared__ float s_yk[64 * 21];   // [ij][c], stride 21 (bank spread)
    __shared__ float s_cat[NW][8][8]; // per-wave batch data
    __shared__ float s_pd[NW][8][20]; // 16 used, stride 20 for b128 align
    __shared__ float s_u[NW][8][20];
    __shared__ float s_v[NW][8][20];

    const int tid  = threadIdx.x;
    const int w    = tid >> 6;
    const int lane = tid & 63;

    // ---------------- block init ----------------
    if (tid < 32) {
        int base = tid & 15, grp = tid >> 4;
        const float* W1 = grp ? wp1 : wv1;
        const float* B1 = grp ? bp1 : bv1;
        const float* W2 = grp ? wp2 : wv2;
        const float* B2 = grp ? bp2 : bv2;
        float v;
        if      (base < 2)  v = W1[base];
        else if (base < 4)  v = B1[base - 2];
        else if (base < 12) v = W2[base - 4];
        else                v = B2[base - 12];
        s_sw[tid] = v;
    }
    if (tid < 128) s_we[tid] = we[tid];
    for (int idx = tid; idx < 640; idx += BLK) s_wc1[idx] = wc1[idx];
    if (tid < 20) s_bc1[tid] = bc1[tid];
    if (tid < 16) s_be[tid]  = be[tid];

    // yk[ij][c] = y(i,j,c) * (wk1@wk2)[c]   (batch-independent, 4 threads per ij)
    {
        int ij = tid >> 2, coff = (tid & 3) * 5;
        int i = ij >> 3, j = ij & 7;
        float m = mask[i * 8 + j];
        float a[4];
#pragma unroll
        for (int q = 0; q < 4; q++) a[q] = relu_(fmaf(m, wm1[q], bm1[q]));
        float b2[20];
#pragma unroll
        for (int c = 0; c < 20; c++) {
            float acc = bm2[c];
#pragma unroll
            for (int q = 0; q < 4; q++) acc = fmaf(a[q], wm2[q * 20 + c], acc);
            b2[c] = relu_(acc);
        }
#pragma unroll
        for (int cc = 0; cc < 5; cc++) {
            int c = coff + cc;
            float acc = bm3[c];
#pragma unroll
            for (int k = 0; k < 20; k++) acc = fmaf(b2[k], wm3[k * 20 + c], acc);
            float y = relu_(acc);
            float wkk = 0.f;
#pragma unroll
            for (int q = 0; q < 8; q++) wkk = fmaf(wk1[c * 8 + q], wk2[q], wkk);
            s_yk[ij * 21 + c] = y * wkk;
        }
    }
    __syncthreads();

    // per-thread loop-invariants
    float yk[20];
#pragma unroll
    for (int c = 0; c < 20; c++) yk[c] = s_yk[lane * 21 + c];

    float c0 = bk2[0];
#pragma unroll
    for (int q = 0; q < 8; q++) c0 = fmaf(bk1[q], wk2[q], c0);

    const int i4 = lane >> 3, j4 = lane & 7;

    // ---------------- main grid-stride loop (Btot % NW == 0) ----------------
    for (int b0 = blockIdx.x * NW; b0 < Btot; b0 += gridDim.x * NW) {
        const int b = b0 + w;

        // stage 1: cat[e][f]  (tiny per-scalar MLPs)
        {
            int e = lane >> 3, f = lane & 7;
            int sb = (f >= 4) ? 16 : 0;
            int q  = f & 3;
            float s  = x[b * 16 + ((f >= 4) ? 8 + e : e)];
            float t0 = relu_(fmaf(s, s_sw[sb + 0], s_sw[sb + 2]));
            float t1 = relu_(fmaf(s, s_sw[sb + 1], s_sw[sb + 3]));
            float val = relu_(fmaf(t0, s_sw[sb + 4 + q],
                              fmaf(t1, s_sw[sb + 8 + q], s_sw[sb + 12 + q])));
            s_cat[w][e][f] = val;
        }
        __syncthreads();

        // stage 2: pd[i][k] = relu(demand[A[i]][k]) + relu(demand[B[i]][k])
#pragma unroll
        for (int r = 0; r < 2; r++) {
            int idx = lane + 64 * r;            // 0..127
            int i = idx >> 4, k = idx & 15;
            int pa = (PA_PACK >> (4 * i)) & 15;
            int pb = (PB_PACK >> (4 * i)) & 15;
            float bek = s_be[k];
            float da = bek, db = bek;
#pragma unroll
            for (int f = 0; f < 8; f++) {
                float wf = s_we[f * 16 + k];
                da = fmaf(s_cat[w][pa][f], wf, da);
                db = fmaf(s_cat[w][pb][f], wf, db);
            }
            s_pd[w][i][k] = relu_(da) + relu_(db);
        }
        __syncthreads();

        // stage 3: u[i][c] = bc1[c] + pd[i]@wc1[:16,c] ; v[i][c] = pd[i]@wc1[16:,c]
        {
            int row = lane >> 2, coff = (lane & 3) * 5;
            int uv = row >> 3, i = row & 7;
            float acc[5];
#pragma unroll
            for (int cc = 0; cc < 5; cc++) acc[cc] = uv ? 0.f : s_bc1[coff + cc];
#pragma unroll
            for (int k = 0; k < 16; k++) {
                float p = s_pd[w][i][k];
#pragma unroll
                for (int cc = 0; cc < 5; cc++)
                    acc[cc] = fmaf(p, s_wc1[(uv * 16 + k) * 20 + coff + cc], acc[cc]);
            }
            float* dst = uv ? &s_v[w][i][0] : &s_u[w][i][0];
#pragma unroll
            for (int cc = 0; cc < 5; cc++) dst[coff + cc] = acc[cc];
        }
        __syncthreads();

        // stage 4: h1 = relu(u[i]+v[j]); s2 = h1@wc2+bc2; z = c0 + relu(s2)·yk
        {
            float h1[20];
#pragma unroll
            for (int k = 0; k < 20; k++)
                h1[k] = relu_(s_u[w][i4][k] + s_v[w][j4][k]);

            float s2[20];
#pragma unroll
            for (int c = 0; c < 20; c++) s2[c] = bc2[c];   // uniform -> SGPR, hoisted
#pragma unroll
            for (int k = 0; k < 20; k++) {
                float hk = h1[k];
#pragma unroll
                for (int c = 0; c < 20; c++)
                    s2[c] = fmaf(hk, wc2[k * 20 + c], s2[c]);  // wc2 uniform -> s_load
            }
            float z = c0;
#pragma unroll
            for (int c = 0; c < 20; c++) z = fmaf(relu_(s2[c]), yk[c], z);

            out[b * 64 + lane] = z;
        }
        __syncthreads();
    }
}

extern "C" void kernel_launch(void* const* d_in, const int* in_sizes, int n_in,
                              void* d_out, int out_size, void* d_ws, size_t ws_size,
                              hipStream_t stream) {
    const float* x    = (const float*)d_in[0];
    const float* mask = (const float*)d_in[1];
    const float* wv1  = (const float*)d_in[2];
    const float* bv1  = (const float*)d_in[3];
    const float* wv2  = (const float*)d_in[4];
    const float* bv2  = (const float*)d_in[5];
    const float* wp1  = (const float*)d_in[6];
    const float* bp1  = (const float*)d_in[7];
    const float* wp2  = (const float*)d_in[8];
    const float* bp2  = (const float*)d_in[9];
    const float* we   = (const float*)d_in[10];
    const float* be   = (const float*)d_in[11];
    const float* wc1  = (const float*)d_in[12];
    const float* bc1  = (const float*)d_in[13];
    const float* wc2  = (const float*)d_in[14];
    const float* bc2  = (const float*)d_in[15];
    const float* wm1  = (const float*)d_in[16];
    const float* bm1  = (const float*)d_in[17];
    const float* wm2  = (const float*)d_in[18];
    const float* bm2  = (const float*)d_in[19];
    const float* wm3  = (const float*)d_in[20];
    const float* bm3  = (const float*)d_in[21];
    const float* wk1  = (const float*)d_in[22];
    const float* bk1  = (const float*)d_in[23];
    const float* wk2  = (const float*)d_in[24];
    const float* bk2  = (const float*)d_in[25];
    float* out = (float*)d_out;

    int Btot = in_sizes[0] / 16;           // 32768
    int grid = (Btot + NW - 1) / NW;
    if (grid > 1024) grid = 1024;          // 8 grid-stride iterations

    frap_kernel<<<grid, BLK, 0, stream>>>(
        x, mask, wv1, bv1, wv2, bv2, wp1, bp1, wp2, bp2, we, be,
        wc1, bc1, wc2, bc2, wm1, bm1, wm2, bm2, wm3, bm3,
        wk1, bk1, wk2, bk2, out, Btot);
}

// Round 2
// 43.030 us; speedup vs baseline: 1.7028x; 1.7028x over previous
//
#include <hip/hip_runtime.h>

#define BLK 256
#define NW 4      // waves per block = batches per block-iteration
#define GRID 2048

typedef float f32x2 __attribute__((ext_vector_type(2)));

__device__ __forceinline__ float relu_(float v) { return fmaxf(v, 0.f); }
// Intra-wave LDS fence: wave is lockstep, so draining our own LDS ops makes
// all lanes' writes visible to all lanes. "memory" clobber stops reordering.
__device__ __forceinline__ void wave_sync() {
    asm volatile("s_waitcnt lgkmcnt(0)" ::: "memory");
}

// PAIRS_A = {0,0,4,1,2,2,6,3} ; PAIRS_B = {4,1,5,5,6,3,7,7} packed as nibbles
#define PA_PACK 0x36221400u
#define PB_PACK 0x77365514u

// ---------------- pre-kernel: batch-independent yk[64][20] and c0 ----------
__global__ void yk_kernel(
    const float* __restrict__ mask,
    const float* __restrict__ wm1, const float* __restrict__ bm1,
    const float* __restrict__ wm2, const float* __restrict__ bm2,
    const float* __restrict__ wm3, const float* __restrict__ bm3,
    const float* __restrict__ wk1, const float* __restrict__ bk1,
    const float* __restrict__ wk2, const float* __restrict__ bk2,
    float* __restrict__ ws)   // ws[0..1279] = yk[ij][c]; ws[1280] = c0
{
    int tid = threadIdx.x;
    int ij = tid >> 2, coff = (tid & 3) * 5;
    int i = ij >> 3, j = ij & 7;
    float m = mask[i * 8 + j];
    float a[4];
#pragma unroll
    for (int q = 0; q < 4; q++) a[q] = relu_(fmaf(m, wm1[q], bm1[q]));
    float b2[20];
#pragma unroll
    for (int c = 0; c < 20; c++) {
        float acc = bm2[c];
#pragma unroll
        for (int q = 0; q < 4; q++) acc = fmaf(a[q], wm2[q * 20 + c], acc);
        b2[c] = relu_(acc);
    }
#pragma unroll
    for (int cc = 0; cc < 5; cc++) {
        int c = coff + cc;
        float acc = bm3[c];
#pragma unroll
        for (int k = 0; k < 20; k++) acc = fmaf(b2[k], wm3[k * 20 + c], acc);
        float y = relu_(acc);
        float wkk = 0.f;
#pragma unroll
        for (int q = 0; q < 8; q++) wkk = fmaf(wk1[c * 8 + q], wk2[q], wkk);
        ws[ij * 20 + c] = y * wkk;
    }
    if (tid == 0) {
        float c0 = bk2[0];
#pragma unroll
        for (int q = 0; q < 8; q++) c0 = fmaf(bk1[q], wk2[q], c0);
        ws[1280] = c0;
    }
}

// ---------------- main kernel ----------------
__global__ __launch_bounds__(BLK, 6) void frap_kernel(
    const float* __restrict__ x,
    const float* __restrict__ wv1, const float* __restrict__ bv1,
    const float* __restrict__ wv2, const float* __restrict__ bv2,
    const float* __restrict__ wp1, const float* __restrict__ bp1,
    const float* __restrict__ wp2, const float* __restrict__ bp2,
    const float* __restrict__ we,  const float* __restrict__ be,
    const float* __restrict__ wc1, const float* __restrict__ bc1,
    const float* __restrict__ wc2, const float* __restrict__ bc2,
    const float* __restrict__ ykg,
    float* __restrict__ out, int Btot)
{
    __shared__ float s_sw[32];         // [veh:16 | pha:16] = w1(2),b1(2),w2(8),b2(4)
    __shared__ float s_wet[16][12];    // we transposed [k][f], stride 12 (2-way=free)
    __shared__ float s_wc1t[20][36];   // wc1 transposed [c][k0..31], stride 36 (conflict-free)
    __shared__ float s_bc1[20];
    __shared__ float s_be[16];
    __shared__ float s_cat[NW][8][8];  // per-wave batch data
    __shared__ float s_pd[NW][8][20];  // 16 used, stride 20: 80B rows, 16B-aligned
    __shared__ float s_u[NW][8][20];
    __shared__ float s_v[NW][8][20];

    const int tid  = threadIdx.x;
    const int w    = tid >> 6;
    const int lane = tid & 63;

    // ---------------- block init ----------------
    if (tid < 32) {
        int base = tid & 15, grp = tid >> 4;
        const float* W1 = grp ? wp1 : wv1;
        const float* B1 = grp ? bp1 : bv1;
        const float* W2 = grp ? wp2 : wv2;
        const float* B2 = grp ? bp2 : bv2;
        float v;
        if      (base < 2)  v = W1[base];
        else if (base < 4)  v = B1[base - 2];
        else if (base < 12) v = W2[base - 4];
        else                v = B2[base - 12];
        s_sw[tid] = v;
    }
    if (tid < 128) s_wet[tid & 15][tid >> 4] = we[tid];        // wet[k][f] = we[f*16+k]
    for (int idx = tid; idx < 640; idx += BLK) {
        int k = idx / 20, c = idx - k * 20;
        s_wc1t[c][k] = wc1[idx];                                // wc1t[c][k] = wc1[k*20+c]
    }
    if (tid < 20) s_bc1[tid] = bc1[tid];
    if (tid < 16) s_be[tid]  = be[tid];
    __syncthreads();

    // per-thread loop-invariants
    float yk[20];
#pragma unroll
    for (int c = 0; c < 20; c++) yk[c] = ykg[lane * 20 + c];
    const float c0 = ykg[1280];   // lane-uniform -> s_load

    const int i4 = lane >> 3, j4 = lane & 7;

    // ---------------- main grid-stride loop (Btot % (grid*NW) == 0) --------
    for (int b0 = blockIdx.x * NW; b0 < Btot; b0 += gridDim.x * NW) {
        const int b = b0 + w;

        // stage 1: cat[e][f]  (tiny per-scalar MLPs)
        {
            int e = lane >> 3, f = lane & 7;
            int sb = (f >= 4) ? 16 : 0;
            int q  = f & 3;
            float s  = x[b * 16 + ((f >= 4) ? 8 + e : e)];
            float t0 = relu_(fmaf(s, s_sw[sb + 0], s_sw[sb + 2]));
            float t1 = relu_(fmaf(s, s_sw[sb + 1], s_sw[sb + 3]));
            s_cat[w][e][f] = relu_(fmaf(t0, s_sw[sb + 4 + q],
                                  fmaf(t1, s_sw[sb + 8 + q], s_sw[sb + 12 + q])));
        }
        wave_sync();

        // stage 2: pd[i][k] = relu(demand[A[i]][k]) + relu(demand[B[i]][k])
#pragma unroll
        for (int r = 0; r < 2; r++) {
            int idx = lane + 64 * r;            // 0..127
            int i = idx >> 4, k = idx & 15;
            int pa = (PA_PACK >> (4 * i)) & 15;
            int pb = (PB_PACK >> (4 * i)) & 15;
            const float* ca = &s_cat[w][pa][0]; // 2x b128
            const float* cb = &s_cat[w][pb][0]; // 2x b128
            const float* wf = &s_wet[k][0];     // 2x b128
            float da = s_be[k], db = da;
#pragma unroll
            for (int f = 0; f < 8; f++) {
                float wv = wf[f];
                da = fmaf(ca[f], wv, da);
                db = fmaf(cb[f], wv, db);
            }
            s_pd[w][i][k] = relu_(da) + relu_(db);
        }
        wave_sync();

        // stage 3: u[i][c] = bc1[c] + pd[i]@wc1[:16,c] ; v[i][c] = pd[i]@wc1[16:,c]
        {
            int row = lane >> 2, cg = lane & 3;
            int uv = row >> 3, i = row & 7;
            const int coff = cg * 5;
            float pdr[16];
#pragma unroll
            for (int k = 0; k < 16; k++) pdr[k] = s_pd[w][i][k];   // 4x b128
            float acc[5];
#pragma unroll
            for (int cc = 0; cc < 5; cc++) acc[cc] = uv ? 0.f : s_bc1[coff + cc];
#pragma unroll
            for (int cc = 0; cc < 5; cc++) {
                const float* wr = &s_wc1t[coff + cc][uv * 16];     // 4x b128, conflict-free
#pragma unroll
                for (int k = 0; k < 16; k++)
                    acc[cc] = fmaf(pdr[k], wr[k], acc[cc]);
            }
            float* dst = uv ? &s_v[w][i][0] : &s_u[w][i][0];
#pragma unroll
            for (int cc = 0; cc < 5; cc++) dst[coff + cc] = acc[cc];
        }
        wave_sync();

        // stage 4: h1 = relu(u[i]+v[j]); s2 = h1@wc2+bc2; z = c0 + relu(s2)·yk
        {
            float h1[20];
#pragma unroll
            for (int k = 0; k < 20; k++)
                h1[k] = relu_(s_u[w][i4][k] + s_v[w][j4][k]);      // 10x b128

            f32x2 s2[10];
#pragma unroll
            for (int c = 0; c < 10; c++) {
                s2[c].x = bc2[2 * c];                               // uniform -> s_load
                s2[c].y = bc2[2 * c + 1];
            }
#pragma unroll
            for (int k = 0; k < 20; k++) {
                f32x2 hk; hk.x = h1[k]; hk.y = h1[k];
                const f32x2* wr = (const f32x2*)&wc2[k * 20];       // uniform -> s_load
#pragma unroll
                for (int c = 0; c < 10; c++)
                    s2[c] += hk * wr[c];                            // v_pk_fma_f32
            }
            float z = c0;
#pragma unroll
            for (int c = 0; c < 10; c++) {
                z = fmaf(relu_(s2[c].x), yk[2 * c],     z);
                z = fmaf(relu_(s2[c].y), yk[2 * c + 1], z);
            }
            out[b * 64 + lane] = z;
        }
        // next-iteration LDS hazards are covered by the stage-1/2 fences
    }
}

extern "C" void kernel_launch(void* const* d_in, const int* in_sizes, int n_in,
                              void* d_out, int out_size, void* d_ws, size_t ws_size,
                              hipStream_t stream) {
    const float* x    = (const float*)d_in[0];
    const float* mask = (const float*)d_in[1];
    const float* wv1  = (const float*)d_in[2];
    const float* bv1  = (const float*)d_in[3];
    const float* wv2  = (const float*)d_in[4];
    const float* bv2  = (const float*)d_in[5];
    const float* wp1  = (const float*)d_in[6];
    const float* bp1  = (const float*)d_in[7];
    const float* wp2  = (const float*)d_in[8];
    const float* bp2  = (const float*)d_in[9];
    const float* we   = (const float*)d_in[10];
    const float* be   = (const float*)d_in[11];
    const float* wc1  = (const float*)d_in[12];
    const float* bc1  = (const float*)d_in[13];
    const float* wc2  = (const float*)d_in[14];
    const float* bc2  = (const float*)d_in[15];
    const float* wm1  = (const float*)d_in[16];
    const float* bm1  = (const float*)d_in[17];
    const float* wm2  = (const float*)d_in[18];
    const float* bm2  = (const float*)d_in[19];
    const float* wm3  = (const float*)d_in[20];
    const float* bm3  = (const float*)d_in[21];
    const float* wk1  = (const float*)d_in[22];
    const float* bk1  = (const float*)d_in[23];
    const float* wk2  = (const float*)d_in[24];
    const float* bk2  = (const float*)d_in[25];
    float* out = (float*)d_out;
    float* ws  = (float*)d_ws;

    int Btot = in_sizes[0] / 16;           // 32768

    yk_kernel<<<1, 256, 0, stream>>>(mask, wm1, bm1, wm2, bm2, wm3, bm3,
                                     wk1, bk1, wk2, bk2, ws);

    int grid = Btot / NW;
    if (grid > GRID) grid = GRID;          // 2048 -> 4 grid-stride iterations

    frap_kernel<<<grid, BLK, 0, stream>>>(
        x, wv1, bv1, wv2, bv2, wp1, bp1, wp2, bp2, we, be,
        wc1, bc1, wc2, bc2, ws, out, Btot);
}